// Round 2
// baseline (1476.308 us; speedup 1.0000x reference)
//
#include <hip/hip_runtime.h>
#include <stdint.h>
#include <stddef.h>

typedef __attribute__((ext_vector_type(8))) short short8;
typedef __attribute__((ext_vector_type(4))) float f32x4;

#define NB 2048
#define HD 512
#define SD 256

#define A_STR 36                 // shorts per A-tile row (32 k + 4 pad) -> 72B stride
#define W_STR 36
#define A_BUF (128 * 36)         // shorts per A buffer
#define W_BUF (512 * 36)         // shorts per W buffer
#define LDS_BYTES (2 * A_BUF * 2 + 2 * W_BUF * 2 + 128 * 4)  // 92672

__device__ __forceinline__ short f2bf(float x) {
  union { float f; uint32_t u; } v; v.f = x;
  uint32_t r = v.u + 0x7fffu + ((v.u >> 16) & 1u);
  return (short)(r >> 16);
}

__device__ __forceinline__ float fast_tanh(float x) {
  x = fminf(fmaxf(x, -15.f), 15.f);
  float e = __expf(2.f * x);
  return __fdividef(e - 1.f, e + 1.f);
}

// ---- Wtb[kb][j][kk] = bf16(W[kb*32+kk][j]) : k-blocked transposed layout ----
__global__ __launch_bounds__(256) void wconv_kernel(const float* __restrict__ W,
                                                    short* __restrict__ Wtb) {
  __shared__ float tile[32][33];
  const int bx = blockIdx.x;
  const int tk0 = (bx & 15) * 32;
  const int tj0 = (bx >> 4) * 32;
  const int lx = threadIdx.x & 31;
  const int ly = threadIdx.x >> 5;
  for (int r = 0; r < 4; ++r) {
    int yy = ly + r * 8;
    tile[yy][lx] = W[(size_t)(tk0 + yy) * HD + tj0 + lx];
  }
  __syncthreads();
  const int kb = tk0 >> 5;
  for (int r = 0; r < 4; ++r) {
    int yy = ly + r * 8;
    Wtb[(size_t)kb * (HD * 32) + (size_t)(tj0 + yy) * 32 + lx] = f2bf(tile[lx][yy]);
  }
}

// ---- alignment[n][s] = sum_j tanh( sum_k hs[n,k,s]*W[k,j] + b[j] ) * c[j] ----
// block: (n, 128-s half). 512 threads = 8 waves (2 s-halves x 4 j-quarters).
// A-tile [128 s][32 k] + W-tile [512 j][32 k], both double-buffered, 72B row
// stride (bank-conflict-free for b128 read/write). Async-split staging: issue
// global loads before the MFMA cluster, LDS-write after it.
__global__ void __launch_bounds__(512, 2)
align_kernel(const float* __restrict__ hs, const short* __restrict__ Wtb,
             const float* __restrict__ bias, const float* __restrict__ ctx,
             float* __restrict__ align_out)
{
  extern __shared__ char smem[];
  short* As = (short*)smem;                          // 2 x [128][36]
  short* Ws = (short*)(smem + 2 * A_BUF * 2);        // 2 x [512][36]
  float* abuf = (float*)(smem + 2 * A_BUF * 2 + 2 * W_BUF * 2);  // [128]

  const int tid = threadIdx.x;
  const int n = blockIdx.x >> 1;
  const int s0 = (blockIdx.x & 1) * 128;
  const float* hsn = hs + (size_t)n * (HD * SD) + s0;

  if (tid < 128) abuf[tid] = 0.f;

  // staging thread maps
  const int a_s  = tid & 127;   // A: s row
  const int a_ko = tid >> 7;    // A: k-octet 0..3
  const int w_ko = tid & 3;     // W: k-octet 0..3
  const int w_j  = tid >> 2;    // W: j row (+128*ii)

  // prologue: stage k-block 0 into buffer 0
  {
    float av[8];
    #pragma unroll
    for (int i = 0; i < 8; ++i)
      av[i] = hsn[(size_t)(a_ko * 8 + i) * SD + a_s];
    short8 pk;
    #pragma unroll
    for (int i = 0; i < 8; ++i) pk[i] = f2bf(av[i]);
    *(short8*)(As + a_s * A_STR + a_ko * 8) = pk;
    #pragma unroll
    for (int ii = 0; ii < 4; ++ii) {
      int j = w_j + 128 * ii;
      *(short8*)(Ws + j * W_STR + w_ko * 8) =
          *(const short8*)(Wtb + (size_t)j * 32 + w_ko * 8);
    }
  }
  __syncthreads();

  const int lane = tid & 63;
  const int wid = tid >> 6;
  const int wm = wid >> 2;   // 0..1 : 64-s half within the 128-s block
  const int wj = wid & 3;    // 0..3 : 128-j quarter
  const int l15 = lane & 15;
  const int lg = lane >> 4;

  f32x4 acc[4][8];
  #pragma unroll
  for (int i = 0; i < 4; ++i)
    #pragma unroll
    for (int p = 0; p < 8; ++p)
      acc[i][p] = (f32x4){0.f, 0.f, 0.f, 0.f};

  for (int kt = 0; kt < 16; ++kt) {
    const int cur = kt & 1;
    const short* Ac = As + cur * A_BUF;
    const short* Wc = Ws + cur * W_BUF;

    // fragment reads (LDS, conflict-free)
    short8 af[4], wf[8];
    const short* Ab = Ac + (wm * 64 + l15) * A_STR + lg * 8;
    #pragma unroll
    for (int i = 0; i < 4; ++i) af[i] = *(const short8*)(Ab + i * 16 * A_STR);
    const short* Wb = Wc + (wj * 128 + l15) * W_STR + lg * 8;
    #pragma unroll
    for (int p = 0; p < 8; ++p) wf[p] = *(const short8*)(Wb + p * 16 * W_STR);

    // issue next-tile global loads NOW (writes happen after the MFMAs)
    float av[8];
    short8 wv[4];
    if (kt < 15) {
      const int kb = (kt + 1) * 32;
      #pragma unroll
      for (int i = 0; i < 8; ++i)
        av[i] = hsn[(size_t)(kb + a_ko * 8 + i) * SD + a_s];
      const short* wsrc = Wtb + (size_t)(kt + 1) * (HD * 32);
      #pragma unroll
      for (int ii = 0; ii < 4; ++ii)
        wv[ii] = *(const short8*)(wsrc + (size_t)(w_j + 128 * ii) * 32 + w_ko * 8);
    }

    // MFMA cluster
    #pragma unroll
    for (int i = 0; i < 4; ++i)
      #pragma unroll
      for (int p = 0; p < 8; ++p)
        acc[i][p] = __builtin_amdgcn_mfma_f32_16x16x32_bf16(af[i], wf[p], acc[i][p], 0, 0, 0);

    // LDS-write the prefetched tile into the other buffer
    if (kt < 15) {
      short* Ad = As + (cur ^ 1) * A_BUF;
      short* Wd = Ws + (cur ^ 1) * W_BUF;
      short8 pk;
      #pragma unroll
      for (int i = 0; i < 8; ++i) pk[i] = f2bf(av[i]);
      *(short8*)(Ad + a_s * A_STR + a_ko * 8) = pk;
      #pragma unroll
      for (int ii = 0; ii < 4; ++ii)
        *(short8*)(Wd + (w_j + 128 * ii) * W_STR + w_ko * 8) = wv[ii];
    }
    __syncthreads();
  }

  // epilogue: tanh + dot with c, reduce over j
  float part[16];
  #pragma unroll
  for (int q = 0; q < 16; ++q) part[q] = 0.f;
  #pragma unroll
  for (int p = 0; p < 8; ++p) {
    const int j = wj * 128 + p * 16 + l15;
    const float bj = bias[j];
    const float cj = ctx[j];
    #pragma unroll
    for (int i = 0; i < 4; ++i)
      #pragma unroll
      for (int r = 0; r < 4; ++r)
        part[i * 4 + r] += fast_tanh(acc[i][p][r] + bj) * cj;
  }
  #pragma unroll
  for (int q = 0; q < 16; ++q) {
    part[q] += __shfl_xor(part[q], 1);
    part[q] += __shfl_xor(part[q], 2);
    part[q] += __shfl_xor(part[q], 4);
    part[q] += __shfl_xor(part[q], 8);
  }
  if (l15 == 0) {
    #pragma unroll
    for (int i = 0; i < 4; ++i)
      #pragma unroll
      for (int r = 0; r < 4; ++r)
        atomicAdd(&abuf[wm * 64 + i * 16 + lg * 4 + r], part[i * 4 + r]);
  }
  __syncthreads();
  if (tid < 128) align_out[(size_t)n * SD + s0 + tid] = abuf[tid];
}

// ---- softmax over s + context[n,h] = sum_s attn[s]*hs[n,h,s] ----
__global__ __launch_bounds__(256) void ctx_kernel(const float* __restrict__ hs,
                                                  const float* __restrict__ align_in,
                                                  float* __restrict__ out)
{
  __shared__ __align__(16) float attn_s[256];
  __shared__ float red[8];
  const int n = blockIdx.x;
  const int t = threadIdx.x;
  const int lane = t & 63, wid = t >> 6;

  float a = align_in[(size_t)n * 256 + t];
  float m = a;
  #pragma unroll
  for (int off = 32; off; off >>= 1) m = fmaxf(m, __shfl_xor(m, off));
  if (lane == 0) red[wid] = m;
  __syncthreads();
  m = fmaxf(fmaxf(red[0], red[1]), fmaxf(red[2], red[3]));
  float e = __expf(a - m);
  float s = e;
  #pragma unroll
  for (int off = 32; off; off >>= 1) s += __shfl_xor(s, off);
  if (lane == 0) red[4 + wid] = s;
  __syncthreads();
  s = red[4] + red[5] + red[6] + red[7];
  attn_s[t] = e / s;
  __syncthreads();

  const int grp = t & 7;      // s-chunk of 32
  const int hrow = t >> 3;    // 0..31
  float av[32];
  #pragma unroll
  for (int u = 0; u < 8; ++u) {
    float4 v = *(const float4*)&attn_s[grp * 32 + u * 4];
    av[4*u+0] = v.x; av[4*u+1] = v.y; av[4*u+2] = v.z; av[4*u+3] = v.w;
  }
  const float* hb = hs + (size_t)n * (HD * SD) + grp * 32;
  for (int it = 0; it < 16; ++it) {
    const int h = it * 32 + hrow;
    const float4* p = (const float4*)(hb + (size_t)h * SD);
    float acc = 0.f;
    #pragma unroll
    for (int u = 0; u < 8; ++u) {
      float4 v = p[u];
      acc += av[4*u+0]*v.x + av[4*u+1]*v.y + av[4*u+2]*v.z + av[4*u+3]*v.w;
    }
    acc += __shfl_xor(acc, 1);
    acc += __shfl_xor(acc, 2);
    acc += __shfl_xor(acc, 4);
    if (grp == 0) out[(size_t)n * HD + h] = acc;
  }
}

extern "C" void kernel_launch(void* const* d_in, const int* in_sizes, int n_in,
                              void* d_out, int out_size, void* d_ws, size_t ws_size,
                              hipStream_t stream) {
  (void)in_sizes; (void)n_in; (void)out_size; (void)ws_size;
  const float* hs = (const float*)d_in[0];
  const float* W  = (const float*)d_in[1];
  const float* b  = (const float*)d_in[2];
  const float* c  = (const float*)d_in[3];
  float* out = (float*)d_out;

  float* align_ws = (float*)d_ws;                                  // 2 MB
  short* Wtb = (short*)((char*)d_ws + (size_t)NB * SD * 4);        // 512 KB

  wconv_kernel<<<256, 256, 0, stream>>>(W, Wtb);
  align_kernel<<<4096, 512, LDS_BYTES, stream>>>(hs, Wtb, b, c, align_ws);
  ctx_kernel<<<NB, 256, 0, stream>>>(hs, align_ws, out);
}

// Round 3
// 932.821 us; speedup vs baseline: 1.5826x; 1.5826x over previous
//
#include <hip/hip_runtime.h>
#include <stdint.h>
#include <stddef.h>

typedef __attribute__((ext_vector_type(8))) short short8;
typedef __attribute__((ext_vector_type(4))) short short4v;
typedef __attribute__((ext_vector_type(4))) float f32x4;

#define NB 2048
#define HD 512
#define SD 256

#define SB 32            // s-rows per block
#define A_STR 40         // shorts per A row (32 k + 8 pad) -> 80B, 16B-aligned rows

__device__ __forceinline__ short f2bf(float x) {
  union { float f; uint32_t u; } v; v.f = x;
  uint32_t r = v.u + 0x7fffu + ((v.u >> 16) & 1u);
  return (short)(r >> 16);
}

__device__ __forceinline__ float fast_tanh(float x) {
  x = fminf(fmaxf(x, -15.f), 15.f);
  float e = __expf(2.f * x);
  return __fdividef(e - 1.f, e + 1.f);
}

// ---- Wtb[kb][j][kk] = bf16(W[kb*32+kk][j]) : k-blocked transposed layout ----
__global__ __launch_bounds__(256) void wconv_kernel(const float* __restrict__ W,
                                                    short* __restrict__ Wtb) {
  __shared__ float tile[32][33];
  const int bx = blockIdx.x;
  const int tk0 = (bx & 15) * 32;
  const int tj0 = (bx >> 4) * 32;
  const int lx = threadIdx.x & 31;
  const int ly = threadIdx.x >> 5;
  for (int r = 0; r < 4; ++r) {
    int yy = ly + r * 8;
    tile[yy][lx] = W[(size_t)(tk0 + yy) * HD + tj0 + lx];
  }
  __syncthreads();
  const int kb = tk0 >> 5;
  for (int r = 0; r < 4; ++r) {
    int yy = ly + r * 8;
    Wtb[(size_t)kb * (HD * 32) + (size_t)(tj0 + yy) * 32 + lx] = f2bf(tile[lx][yy]);
  }
}

// ---- alignment[n][s] = sum_j tanh( sum_k hs[n,k,s]*W[k,j] + b[j] ) * c[j] ----
// Block: 32 s x 512 j, 256 threads = 4 waves, wave = 128-j slice x all 32 s.
// A (32s x 32k bf16) double-buffered in 5 KB LDS; W fragments read directly
// from L2-resident Wtb (1KB contiguous per wave-load). ~3 blocks/CU resident:
// cross-block overlap hides barrier/vmcnt stalls structurally.
__global__ void __launch_bounds__(256, 3)
align_kernel(const float* __restrict__ hs, const short* __restrict__ Wtb,
             const float* __restrict__ bias, const float* __restrict__ ctx,
             float* __restrict__ align_out)
{
  __shared__ short As[2][SB * A_STR];
  __shared__ float abuf[SB];

  const int tid = threadIdx.x;
  const int n = blockIdx.x >> 3;
  const int s0 = (blockIdx.x & 7) * SB;
  const float* hsn = hs + (size_t)n * (HD * SD) + s0;

  if (tid < SB) abuf[tid] = 0.f;

  // A staging map: thread loads a 4-k column at one s
  const int a_s = tid & 31;
  const int a_kq = tid >> 5;   // 0..7 -> k = a_kq*4 + u

  // prologue: stage k-step 0 into buffer 0
  {
    const float* src = hsn + (size_t)(a_kq * 4) * SD + a_s;
    float v0 = src[0], v1 = src[SD], v2 = src[2 * SD], v3 = src[3 * SD];
    short4v pk; pk[0] = f2bf(v0); pk[1] = f2bf(v1); pk[2] = f2bf(v2); pk[3] = f2bf(v3);
    *(short4v*)&As[0][a_s * A_STR + a_kq * 4] = pk;
  }
  __syncthreads();

  const int lane = tid & 63;
  const int l15 = lane & 15;
  const int lg = lane >> 4;
  const int wid = tid >> 6;
  const int jb = wid * 128;

  f32x4 acc[2][8];
  #pragma unroll
  for (int i = 0; i < 2; ++i)
    #pragma unroll
    for (int p = 0; p < 8; ++p)
      acc[i][p] = (f32x4){0.f, 0.f, 0.f, 0.f};

  // per-lane W fragment base: row j = jb + p*16 + l15, k-octet lg
  const short* wbase = Wtb + (size_t)(jb + l15) * 32 + lg * 8;

  for (int kt = 0; kt < 16; ++kt) {
    const int cur = kt & 1;

    // B(j)-fragments straight from global (L2-resident, 1KB contiguous/wave)
    short8 wf[8];
    const short* wk = wbase + (size_t)kt * (HD * 32);
    #pragma unroll
    for (int p = 0; p < 8; ++p)
      wf[p] = *(const short8*)(wk + p * (16 * 32));

    // A(s)-fragments from LDS (b128, 16B-aligned rows)
    short8 af[2];
    #pragma unroll
    for (int i = 0; i < 2; ++i)
      af[i] = *(const short8*)&As[cur][(i * 16 + l15) * A_STR + lg * 8];

    // stage k-step kt+1 into the other buffer
    if (kt < 15) {
      const float* src = hsn + (size_t)((kt + 1) * 32 + a_kq * 4) * SD + a_s;
      float v0 = src[0], v1 = src[SD], v2 = src[2 * SD], v3 = src[3 * SD];
      short4v pk; pk[0] = f2bf(v0); pk[1] = f2bf(v1); pk[2] = f2bf(v2); pk[3] = f2bf(v3);
      *(short4v*)&As[cur ^ 1][a_s * A_STR + a_kq * 4] = pk;
    }

    // MFMA: D[j][s] += Wfrag(16j x 32k) * Afrag(32k x 16s)
    #pragma unroll
    for (int i = 0; i < 2; ++i)
      #pragma unroll
      for (int p = 0; p < 8; ++p)
        acc[i][p] = __builtin_amdgcn_mfma_f32_16x16x32_bf16(wf[p], af[i], acc[i][p], 0, 0, 0);

    __syncthreads();
  }

  // epilogue: D rows = j (lg*4 + r within fragment), cols = s (l15).
  // tanh + *c, sum over this wave's 128 j in-lane, then 2 shuffles over lg.
  float part0 = 0.f, part1 = 0.f;
  #pragma unroll
  for (int p = 0; p < 8; ++p) {
    const int j = jb + p * 16 + lg * 4;
    f32x4 bv = *(const f32x4*)(bias + j);
    f32x4 cv = *(const f32x4*)(ctx + j);
    #pragma unroll
    for (int r = 0; r < 4; ++r) {
      part0 += fast_tanh(acc[0][p][r] + bv[r]) * cv[r];
      part1 += fast_tanh(acc[1][p][r] + bv[r]) * cv[r];
    }
  }
  part0 += __shfl_xor(part0, 16); part0 += __shfl_xor(part0, 32);
  part1 += __shfl_xor(part1, 16); part1 += __shfl_xor(part1, 32);
  if (lane < 16) {
    atomicAdd(&abuf[l15], part0);
    atomicAdd(&abuf[16 + l15], part1);
  }
  __syncthreads();
  if (tid < SB) align_out[(size_t)n * SD + s0 + tid] = abuf[tid];
}

// ---- softmax over s + context[n,h] = sum_s attn[s]*hs[n,h,s] ----
__global__ __launch_bounds__(256) void ctx_kernel(const float* __restrict__ hs,
                                                  const float* __restrict__ align_in,
                                                  float* __restrict__ out)
{
  __shared__ __align__(16) float attn_s[256];
  __shared__ float red[8];
  const int n = blockIdx.x;
  const int t = threadIdx.x;
  const int lane = t & 63, wid = t >> 6;

  float a = align_in[(size_t)n * 256 + t];
  float m = a;
  #pragma unroll
  for (int off = 32; off; off >>= 1) m = fmaxf(m, __shfl_xor(m, off));
  if (lane == 0) red[wid] = m;
  __syncthreads();
  m = fmaxf(fmaxf(red[0], red[1]), fmaxf(red[2], red[3]));
  float e = __expf(a - m);
  float s = e;
  #pragma unroll
  for (int off = 32; off; off >>= 1) s += __shfl_xor(s, off);
  if (lane == 0) red[4 + wid] = s;
  __syncthreads();
  s = red[4] + red[5] + red[6] + red[7];
  attn_s[t] = e / s;
  __syncthreads();

  const int grp = t & 7;      // s-chunk of 32
  const int hrow = t >> 3;    // 0..31
  float av[32];
  #pragma unroll
  for (int u = 0; u < 8; ++u) {
    float4 v = *(const float4*)&attn_s[grp * 32 + u * 4];
    av[4*u+0] = v.x; av[4*u+1] = v.y; av[4*u+2] = v.z; av[4*u+3] = v.w;
  }
  const float* hb = hs + (size_t)n * (HD * SD) + grp * 32;
  for (int it = 0; it < 16; ++it) {
    const int h = it * 32 + hrow;
    const float4* p = (const float4*)(hb + (size_t)h * SD);
    float acc = 0.f;
    #pragma unroll
    for (int u = 0; u < 8; ++u) {
      float4 v = p[u];
      acc += av[4*u+0]*v.x + av[4*u+1]*v.y + av[4*u+2]*v.z + av[4*u+3]*v.w;
    }
    acc += __shfl_xor(acc, 1);
    acc += __shfl_xor(acc, 2);
    acc += __shfl_xor(acc, 4);
    if (grp == 0) out[(size_t)n * HD + h] = acc;
  }
}

extern "C" void kernel_launch(void* const* d_in, const int* in_sizes, int n_in,
                              void* d_out, int out_size, void* d_ws, size_t ws_size,
                              hipStream_t stream) {
  (void)in_sizes; (void)n_in; (void)out_size; (void)ws_size;
  const float* hs = (const float*)d_in[0];
  const float* W  = (const float*)d_in[1];
  const float* b  = (const float*)d_in[2];
  const float* c  = (const float*)d_in[3];
  float* out = (float*)d_out;

  float* align_ws = (float*)d_ws;                                  // 2 MB
  short* Wtb = (short*)((char*)d_ws + (size_t)NB * SD * 4);        // 512 KB

  wconv_kernel<<<256, 256, 0, stream>>>(W, Wtb);
  align_kernel<<<NB * 8, 256, 0, stream>>>(hs, Wtb, b, c, align_ws);
  ctx_kernel<<<NB, 256, 0, stream>>>(hs, align_ws, out);
}

// Round 4
// 846.838 us; speedup vs baseline: 1.7433x; 1.1015x over previous
//
#include <hip/hip_runtime.h>
#include <hip/hip_bf16.h>
#include <stdint.h>
#include <stddef.h>

typedef __attribute__((ext_vector_type(8))) short short8;
typedef __attribute__((ext_vector_type(4))) float f32x4;

#define NB 2048
#define HD 512
#define SD 256

__device__ __forceinline__ short f2bf(float x) {
  __hip_bfloat16 h = __float2bfloat16(x);
  return *reinterpret_cast<short*>(&h);
}

__device__ __forceinline__ float fast_tanh(float x) {
  x = fminf(fmaxf(x, -15.f), 15.f);
  float e = __expf(2.f * x);
  return __fdividef(e - 1.f, e + 1.f);
}

// ---- Wtb[kb][j][kk] = bf16(W[kb*32+kk][j]) : k-blocked transposed layout ----
__global__ __launch_bounds__(256) void wconv_kernel(const float* __restrict__ W,
                                                    short* __restrict__ Wtb) {
  __shared__ float tile[32][33];
  const int bx = blockIdx.x;
  const int tk0 = (bx & 15) * 32;
  const int tj0 = (bx >> 4) * 32;
  const int lx = threadIdx.x & 31;
  const int ly = threadIdx.x >> 5;
  for (int r = 0; r < 4; ++r) {
    int yy = ly + r * 8;
    tile[yy][lx] = W[(size_t)(tk0 + yy) * HD + tj0 + lx];
  }
  __syncthreads();
  const int kb = tk0 >> 5;
  for (int r = 0; r < 4; ++r) {
    int yy = ly + r * 8;
    Wtb[(size_t)kb * (HD * 32) + (size_t)(tj0 + yy) * 32 + lx] = f2bf(tile[lx][yy]);
  }
}

// ---- alignment[n][s] = sum_j tanh( sum_k hs[n,k,s]*W[k,j] + b[j] ) * c[j] ----
// Block = 4 waves, all on the SAME 64-s chunk, each owning a 128-j slice.
// NO LDS / NO barriers in the k-loop: A-fragments are built by per-lane
// scalar global loads in MFMA layout (waves 1-3 hit L1/L2 on wave 0's lines);
// W-fragments are contiguous 1KB wave-loads from L2-resident Wtb.
// 2 waves/SIMD; one wave's load latency is hidden by the other's 32 MFMAs.
__global__ void __launch_bounds__(256, 2)
align_kernel(const float* __restrict__ hs, const short* __restrict__ Wtb,
             const float* __restrict__ bias, const float* __restrict__ ctx,
             float* __restrict__ align_out)
{
  __shared__ float abuf[64];

  const int tid = threadIdx.x;
  const int n = blockIdx.x >> 2;
  const int s0 = (blockIdx.x & 3) * 64;
  const int lane = tid & 63;
  const int wid = tid >> 6;
  const int l15 = lane & 15;
  const int lg = lane >> 4;
  const int jb = wid * 128;

  if (tid < 64) abuf[tid] = 0.f;
  __syncthreads();

  // per-lane bases
  // A (B-operand of mfma): lane needs hs[n][k = kt*32 + lg*8 + e][s0 + i*16 + l15]
  const float* hsA = hs + (size_t)n * (HD * SD) + s0 + l15 + (size_t)(lg * 8) * SD;
  // W (A-operand of mfma): lane needs Wtb[kt][j = jb + p*16 + l15][lg*8 + e]
  const short* wbase = Wtb + (size_t)(jb + l15) * 32 + lg * 8;

  f32x4 acc[4][8];
  #pragma unroll
  for (int i = 0; i < 4; ++i)
    #pragma unroll
    for (int p = 0; p < 8; ++p)
      acc[i][p] = (f32x4){0.f, 0.f, 0.f, 0.f};

  for (int kt = 0; kt < 16; ++kt) {
    // W fragments: 8 x dwordx4, each a contiguous 1KB wave-read (L2)
    short8 wf[8];
    const short* wk = wbase + (size_t)kt * (HD * 32);
    #pragma unroll
    for (int p = 0; p < 8; ++p)
      wf[p] = *(const short8*)(wk + p * (16 * 32));

    // A fragments: 4 x (8 scalar f32 loads -> pack to bf16x8)
    short8 af[4];
    const float* ak = hsA + (size_t)(kt * 32) * SD;
    #pragma unroll
    for (int i = 0; i < 4; ++i) {
      float v[8];
      #pragma unroll
      for (int e = 0; e < 8; ++e)
        v[e] = ak[(size_t)e * SD + i * 16];
      short8 pk;
      #pragma unroll
      for (int e = 0; e < 8; ++e) pk[e] = f2bf(v[e]);
      af[i] = pk;
    }

    // 32 independent MFMAs: D[j][s] += Wfrag(16j x 32k) * Afrag(32k x 16s)
    #pragma unroll
    for (int i = 0; i < 4; ++i)
      #pragma unroll
      for (int p = 0; p < 8; ++p)
        acc[i][p] = __builtin_amdgcn_mfma_f32_16x16x32_bf16(wf[p], af[i], acc[i][p], 0, 0, 0);
  }

  // epilogue: D rows = j (lg*4 + r per fragment), cols = s (l15).
  // tanh + *c, in-lane sum over this wave's 128 j, 2 shuffles over lg groups,
  // then one LDS atomic reduction across the 4 j-slice waves.
  float part[4] = {0.f, 0.f, 0.f, 0.f};
  #pragma unroll
  for (int p = 0; p < 8; ++p) {
    const int j = jb + p * 16 + lg * 4;
    f32x4 bv = *(const f32x4*)(bias + j);
    f32x4 cv = *(const f32x4*)(ctx + j);
    #pragma unroll
    for (int i = 0; i < 4; ++i)
      #pragma unroll
      for (int r = 0; r < 4; ++r)
        part[i] += fast_tanh(acc[i][p][r] + bv[r]) * cv[r];
  }
  #pragma unroll
  for (int i = 0; i < 4; ++i) {
    part[i] += __shfl_xor(part[i], 16);
    part[i] += __shfl_xor(part[i], 32);
  }
  if (lg == 0) {
    #pragma unroll
    for (int i = 0; i < 4; ++i)
      atomicAdd(&abuf[i * 16 + l15], part[i]);
  }
  __syncthreads();
  if (tid < 64) align_out[(size_t)n * SD + s0 + tid] = abuf[tid];
}

// ---- softmax over s + context[n,h] = sum_s attn[s]*hs[n,h,s] ----
__global__ __launch_bounds__(256) void ctx_kernel(const float* __restrict__ hs,
                                                  const float* __restrict__ align_in,
                                                  float* __restrict__ out)
{
  __shared__ __align__(16) float attn_s[256];
  __shared__ float red[8];
  const int n = blockIdx.x;
  const int t = threadIdx.x;
  const int lane = t & 63, wid = t >> 6;

  float a = align_in[(size_t)n * 256 + t];
  float m = a;
  #pragma unroll
  for (int off = 32; off; off >>= 1) m = fmaxf(m, __shfl_xor(m, off));
  if (lane == 0) red[wid] = m;
  __syncthreads();
  m = fmaxf(fmaxf(red[0], red[1]), fmaxf(red[2], red[3]));
  float e = __expf(a - m);
  float s = e;
  #pragma unroll
  for (int off = 32; off; off >>= 1) s += __shfl_xor(s, off);
  if (lane == 0) red[4 + wid] = s;
  __syncthreads();
  s = red[4] + red[5] + red[6] + red[7];
  attn_s[t] = e / s;
  __syncthreads();

  const int grp = t & 7;      // s-chunk of 32
  const int hrow = t >> 3;    // 0..31
  float av[32];
  #pragma unroll
  for (int u = 0; u < 8; ++u) {
    float4 v = *(const float4*)&attn_s[grp * 32 + u * 4];
    av[4*u+0] = v.x; av[4*u+1] = v.y; av[4*u+2] = v.z; av[4*u+3] = v.w;
  }
  const float* hb = hs + (size_t)n * (HD * SD) + grp * 32;
  for (int it = 0; it < 16; ++it) {
    const int h = it * 32 + hrow;
    const float4* p = (const float4*)(hb + (size_t)h * SD);
    float acc = 0.f;
    #pragma unroll
    for (int u = 0; u < 8; ++u) {
      float4 v = p[u];
      acc += av[4*u+0]*v.x + av[4*u+1]*v.y + av[4*u+2]*v.z + av[4*u+3]*v.w;
    }
    acc += __shfl_xor(acc, 1);
    acc += __shfl_xor(acc, 2);
    acc += __shfl_xor(acc, 4);
    if (grp == 0) out[(size_t)n * HD + h] = acc;
  }
}

extern "C" void kernel_launch(void* const* d_in, const int* in_sizes, int n_in,
                              void* d_out, int out_size, void* d_ws, size_t ws_size,
                              hipStream_t stream) {
  (void)in_sizes; (void)n_in; (void)out_size; (void)ws_size;
  const float* hs = (const float*)d_in[0];
  const float* W  = (const float*)d_in[1];
  const float* b  = (const float*)d_in[2];
  const float* c  = (const float*)d_in[3];
  float* out = (float*)d_out;

  float* align_ws = (float*)d_ws;                                  // 2 MB
  short* Wtb = (short*)((char*)d_ws + (size_t)NB * SD * 4);        // 512 KB

  wconv_kernel<<<256, 256, 0, stream>>>(W, Wtb);
  align_kernel<<<NB * 4, 256, 0, stream>>>(hs, Wtb, b, c, align_ws);
  ctx_kernel<<<NB, 256, 0, stream>>>(hs, align_ws, out);
}